// Round 4
// baseline (628.375 us; speedup 1.0000x reference)
//
#include <hip/hip_runtime.h>
#include <stdint.h>

// Problem constants
#define M_DIM 4096
#define K_DIM 4096
#define N_DIM 11008
#define N_GROUPS 32   // K_DIM / 128

typedef __attribute__((ext_vector_type(8))) short short8;    // 8 bf16 bit-patterns (4 VGPRs)
typedef __attribute__((ext_vector_type(4))) float floatx4;   // 16x16 MFMA accumulator
typedef __attribute__((ext_vector_type(16))) float floatx16; // 32x32 MFMA accumulator

__device__ __forceinline__ unsigned short f32_to_bf16(float f) {
    unsigned int u = __float_as_uint(f);
    unsigned int rounding = 0x7FFFu + ((u >> 16) & 1u);  // RNE
    return (unsigned short)((u + rounding) >> 16);
}

// ---------------------------------------------------------------------------
// Mt[i][j] = M[j][i] where M = H*diag(s2)*H*diag(s1) applied to x:
// z_i = sum_j M^T[i,j] x_j ; Mt[i][j] = s1[j]/128 * sum_a (-1)^(popc(i&a)+popc(a&j)) s2[a]
__global__ __launch_bounds__(128) void make_M_kernel(
    const float* __restrict__ signs1, const float* __restrict__ signs2,
    unsigned short* __restrict__ Mt)   // [128][128] bf16
{
    const int i = blockIdx.x;    // z-column
    const int j = threadIdx.x;   // x-row
    __shared__ float s2s[128];
    s2s[j] = signs2[j];
    __syncthreads();
    float acc = 0.f;
#pragma unroll 8
    for (int a = 0; a < 128; ++a) {
        int par = (__popc(i & a) + __popc(a & j)) & 1;
        acc += par ? -s2s[a] : s2s[a];
    }
    Mt[i * 128 + j] = f32_to_bf16(signs1[j] * acc * (1.0f / 128.0f));
}

// ---------------------------------------------------------------------------
// Z = X * M per 128-group (block-diagonal). R4 rewrite:
// one block = 256 rows x 1 group (4 sub-tiles of 64 rows), 512 threads.
// Mt staged ONCE per block, B-fragments hoisted to registers; z stores are
// LDS-staged -> uint4 coalesced (old version: 32 scattered 2-B stores/thread).
__global__ __launch_bounds__(512) void transform_x_kernel(
    const float* __restrict__ x,            // [M_DIM][K_DIM] fp32
    const unsigned short* __restrict__ Mt,  // [128][128] bf16
    unsigned short* __restrict__ z)         // [M_DIM][K_DIM] bf16
{
    __shared__ __align__(16) short Ms[128 * 136];
    __shared__ __align__(16) short Xs[64 * 136];
    __shared__ __align__(16) short Ls[64 * 136];

    const int tid = threadIdx.x;
    const int wave = tid >> 6, lane = tid & 63;
    const int col16 = lane & 15, quad = lane >> 4;
    const int wr = wave >> 2;          // 0..1: 32-row slice
    const int wc = wave & 3;           // 0..3: 32-col slice
    const int g = blockIdx.x & 31;
    const int mblk = blockIdx.x >> 5;  // 0..15
    const int c0 = g * 128;
    const int mBase = mblk * 256;

    // stage Mt once (128 x 128 bf16 = 2048 uint4 chunks)
#pragma unroll
    for (int it = 0; it < 4; ++it) {
        int ch = tid + 512 * it;
        int row = ch >> 4, cc = ch & 15;
        *(uint4*)(Ms + row * 136 + cc * 8) = *(const uint4*)(Mt + (size_t)ch * 8);
    }
    __syncthreads();

    // hoist this wave's B-fragments (2 n-tiles x 4 ksteps) into registers
    short8 bf[2][4];
#pragma unroll
    for (int ni = 0; ni < 2; ++ni)
#pragma unroll
        for (int ks = 0; ks < 4; ++ks)
            bf[ni][ks] = *(const short8*)(Ms + (wc * 32 + ni * 16 + col16) * 136 + ks * 32 + quad * 8);

    for (int s = 0; s < 4; ++s) {
        __syncthreads();   // prior sub-tile's Xs reads + Ls stores complete
        // stage X sub-tile (64 x 128 fp32 -> bf16): 2048 float4, 4/thread
#pragma unroll
        for (int it = 0; it < 4; ++it) {
            int idx = tid + 512 * it;
            int row = idx >> 5, c4 = idx & 31;
            float4 v = *(const float4*)(x + (size_t)(mBase + s * 64 + row) * K_DIM + c0 + c4 * 4);
            uint2 o;
            o.x = (unsigned)f32_to_bf16(v.x) | ((unsigned)f32_to_bf16(v.y) << 16);
            o.y = (unsigned)f32_to_bf16(v.z) | ((unsigned)f32_to_bf16(v.w) << 16);
            *(uint2*)(Xs + row * 136 + c4 * 4) = o;
        }
        __syncthreads();

        // wave computes 32 rows x 32 cols: 2x2 tiles x 4 ksteps
        short8 af[2][4];
#pragma unroll
        for (int mi = 0; mi < 2; ++mi)
#pragma unroll
            for (int ks = 0; ks < 4; ++ks)
                af[mi][ks] = *(const short8*)(Xs + (wr * 32 + mi * 16 + col16) * 136 + ks * 32 + quad * 8);
        floatx4 acc2[2][2] = {};
#pragma unroll
        for (int ks = 0; ks < 4; ++ks)
#pragma unroll
            for (int mi = 0; mi < 2; ++mi)
#pragma unroll
                for (int ni = 0; ni < 2; ++ni)
                    acc2[mi][ni] = __builtin_amdgcn_mfma_f32_16x16x32_bf16(
                        af[mi][ks], bf[ni][ks], acc2[mi][ni], 0, 0, 0);

        // acc -> Ls (bf16), C/D layout: col=lane&15, row=quad*4+r
#pragma unroll
        for (int mi = 0; mi < 2; ++mi)
#pragma unroll
            for (int ni = 0; ni < 2; ++ni)
#pragma unroll
                for (int r = 0; r < 4; ++r)
                    Ls[(wr * 32 + mi * 16 + quad * 4 + r) * 136 + wc * 32 + ni * 16 + col16] =
                        f32_to_bf16(acc2[mi][ni][r]);
        __syncthreads();

        // coalesced store: 64 rows x 16 uint4-chunks, 2/thread
#pragma unroll
        for (int it = 0; it < 2; ++it) {
            int idx = tid + 512 * it;
            int row = idx >> 4, cc = idx & 15;
            uint4 v = *(const uint4*)(Ls + row * 136 + cc * 8);
            *(uint4*)(z + (size_t)(mBase + s * 64 + row) * K_DIM + c0 + cc * 8) = v;
        }
    }
}

// ---------------------------------------------------------------------------
// Dequant is a pure LUT: w'[n, g*128+j] = norms[n,g] * centroids[idx].
// One block per output row (2048 ints = 4096 elems). 8 ints/thread.
// (unchanged this round — control)
__global__ __launch_bounds__(256) void dequant_lut_kernel(
    const int* __restrict__ packed,      // [N_DIM][2048]
    const float* __restrict__ norms,     // [N_DIM][N_GROUPS]
    const float* __restrict__ centroids, // [16]
    unsigned int* __restrict__ w_out)    // [N_DIM][2048] two bf16 per uint
{
    __shared__ float2 lut[256];
    const int tid = threadIdx.x;
    lut[tid] = make_float2(centroids[tid & 15], centroids[tid >> 4]);
    __syncthreads();

    const int row = blockIdx.x;
    const int g = tid >> 3;                 // 8 threads per 64-int group
    const float nrm = norms[row * N_GROUPS + g];
    const int* prow = packed + (size_t)row * 2048 + tid * 8;
    int4 pa = *(const int4*)(prow);
    int4 pb = *(const int4*)(prow + 4);
    int v[8] = {pa.x, pa.y, pa.z, pa.w, pb.x, pb.y, pb.z, pb.w};
    unsigned o[8];
#pragma unroll
    for (int q = 0; q < 8; ++q) {
        float2 c = lut[v[q] & 255];
        o[q] = (unsigned)f32_to_bf16(c.x * nrm) | ((unsigned)f32_to_bf16(c.y * nrm) << 16);
    }
    unsigned* orow = w_out + (size_t)row * 2048 + tid * 8;
    *(uint4*)(orow)     = make_uint4(o[0], o[1], o[2], o[3]);
    *(uint4*)(orow + 4) = make_uint4(o[4], o[5], o[6], o[7]);
}

// ---------------------------------------------------------------------------
// GEMM: C[M][N] = Z[M][K] * W[N][K]^T + bias.
// 256x256 8-phase schedule; R4: core swapped to mfma_f32_32x32x16_bf16
// (-17% MFMA cycles, half the issue slots). Staging, XOR swizzle, vmcnt
// ledger, barriers unchanged from R3.
#define BM 256
#define BN 256
#define BK 64

typedef const __attribute__((address_space(1))) void* gvp_t;
typedef __attribute__((address_space(3))) void* svp_t;

#define BARRIER() do { asm volatile("" ::: "memory"); __builtin_amdgcn_s_barrier(); \
                       asm volatile("" ::: "memory"); } while (0)
#define VM8()   asm volatile("s_waitcnt vmcnt(8)" ::: "memory")
#define VM4()   asm volatile("s_waitcnt vmcnt(4)" ::: "memory")
#define VM2()   asm volatile("s_waitcnt vmcnt(2)" ::: "memory")
#define VM0()   asm volatile("s_waitcnt vmcnt(0)" ::: "memory")
#define PRIO1() __builtin_amdgcn_s_setprio(1)
#define PRIO0() __builtin_amdgcn_s_setprio(0)

// 32x32x16 fragment reads. Per-lane row = base + (lane&31); k-chunk for
// kstep ks, lane-half hh = lane>>5 is global chunk (ks*2|hh); LDS slot =
// (chunk ^ (row&7)) where row&7 == lane&7 (bases are multiples of 32).
__device__ __forceinline__ void read_a32(short8 (&dst)[2][4], const short* rb, int hh, int r7) {
#pragma unroll
    for (int mi = 0; mi < 2; ++mi)
#pragma unroll
        for (int k = 0; k < 4; ++k)
            dst[mi][k] = *(const short8*)(rb + mi * 2048 + ((((k << 1) | hh) ^ r7) << 3));
}
__device__ __forceinline__ void read_b32(short8 (&dst)[4], const short* rb, int hh, int r7) {
#pragma unroll
    for (int k = 0; k < 4; ++k)
        dst[k] = *(const short8*)(rb + ((((k << 1) | hh) ^ r7) << 3));
}
// 8 MFMAs: one C-quadrant (64x32 = 2 m-tiles) over K=64. k outer so the two
// acc chains alternate (2 independent chains x 4 deep per wave).
__device__ __forceinline__ void mfma_q32(floatx16 (&acc)[2],
                                         const short8 (&a)[2][4], const short8 (&b)[4]) {
#pragma unroll
    for (int k = 0; k < 4; ++k)
#pragma unroll
        for (int mi = 0; mi < 2; ++mi)
            acc[mi] = __builtin_amdgcn_mfma_f32_32x32x16_bf16(a[mi][k], b[k], acc[mi], 0, 0, 0);
}

__global__ __launch_bounds__(512, 2) void gemm_bt_kernel(
    const unsigned short* __restrict__ A,   // [M_DIM][K_DIM] bf16 bits (= Z)
    const unsigned short* __restrict__ B,   // [N_DIM][K_DIM] bf16 bits (= W')
    const float* __restrict__ bias,         // [N_DIM]
    float* __restrict__ C)                  // [M_DIM][N_DIM]
{
    // LDS: A[2 buf][256][64] | B[2 buf][256][64] bf16 = 128 KiB.
    // A rows quarter-permuted: LDS row = qm*128 + wm*64 + r (r in 0..63).
    // B rows: LDS row = qn*128 + wn*32 + c (c in 0..31).
    __shared__ __align__(16) short smem[65536];
    short* As = smem;              // + buf*16384 (shorts)
    short* Bs = smem + 32768;

    const int tid = threadIdx.x;
    const int w = tid >> 6, lane = tid & 63;
    const int wm = w >> 2, wn = w & 3;          // 2 x 4 wave grid
    const int l31 = lane & 31, hh = lane >> 5, r7 = lane & 7;

    const int bid = blockIdx.x;
    const int mt = bid & 15;                    // 0..15 (M/BM = 16 exactly)
    const int nt = bid >> 4;                    // 0..42
    const int m0 = mt * BM, n0 = nt * BN;

    // Staging: linear LDS dest; source column chunk XOR-swizzled so
    // LDS[row][chunk c] = global[row][c ^ (row&7)] (measured 0 conflicts).
    const int gc = (lane & 7) ^ (lane >> 3);
    const unsigned short* aSrc = A + (size_t)(m0 + w * 8 + (lane >> 3)) * K_DIM + gc * 8;
    const unsigned short* bSrc = B + (size_t)(n0 + (w >> 2) * 64 + (w & 3) * 8 + (lane >> 3)) * K_DIM + gc * 8;
    const int wOff = w * 512;

#define STAGE_A(BUF, H, KT) do { \
    __builtin_amdgcn_global_load_lds((gvp_t)(aSrc + (size_t)((H) * 64) * K_DIM + (KT) * 64), \
        (svp_t)(As + (BUF) * 16384 + (H) * 8192 + wOff), 16, 0, 0); \
    __builtin_amdgcn_global_load_lds((gvp_t)(aSrc + (size_t)((H) * 64 + 128) * K_DIM + (KT) * 64), \
        (svp_t)(As + (BUF) * 16384 + (H) * 8192 + 4096 + wOff), 16, 0, 0); \
} while (0)
#define STAGE_B(BUF, H, KT) do { \
    __builtin_amdgcn_global_load_lds((gvp_t)(bSrc + (size_t)((H) * 32) * K_DIM + (KT) * 64), \
        (svp_t)(Bs + (BUF) * 16384 + (H) * 8192 + wOff), 16, 0, 0); \
    __builtin_amdgcn_global_load_lds((gvp_t)(bSrc + (size_t)((H) * 32 + 128) * K_DIM + (KT) * 64), \
        (svp_t)(Bs + (BUF) * 16384 + (H) * 8192 + 4096 + wOff), 16, 0, 0); \
} while (0)

    // Fragment-read bases (per-lane row folded in; buf/qm add constant offsets).
    const short* aR = As + (wm * 64 + l31) * 64;
    const short* bR = Bs + (wn * 32 + l31) * 64;

    short8 a0[2][4], a1[2][4], b0[4], b1[4];
    floatx16 acc[2][2][2];   // [qm][qn][mi]
#pragma unroll
    for (int i0 = 0; i0 < 2; ++i0)
#pragma unroll
        for (int i1 = 0; i1 < 2; ++i1)
#pragma unroll
            for (int i2 = 0; i2 < 2; ++i2)
                acc[i0][i1][i2] = (floatx16)0.0f;

    // ------------------------------------------------------------------
    // SYNC LEDGER (identical to R3 — stage points, read points, and all
    // vmcnt values unchanged; only the ds_read addressing/widths differ,
    // with the same per-phase instruction counts 12/4/0/12/12/4/0/12).
    // ------------------------------------------------------------------

    // Prologue = stages of virtual phases 2..7, then ph8 role.
    STAGE_A(0, 0, 0); STAGE_B(0, 0, 0);
    STAGE_A(0, 1, 0); STAGE_B(0, 1, 0);
    STAGE_A(1, 0, 1); STAGE_B(1, 0, 1);
    VM8();
    BARRIER();
    read_a32(a0, aR, hh, r7); read_b32(b0, bR, hh, r7);
    STAGE_A(1, 1, 1);
    VM8();
    BARRIER();

    const int NIT = K_DIM / (2 * BK) - 1;   // 31 full iterations + drain
    for (int i = 0; i < NIT; ++i) {
        const int t = 2 * i;
        // ph1: Q00(a0,b0) | reads a1 | stage B1.h1 | VM8
        read_a32(a1, aR + 8192, hh, r7);
        PRIO1(); mfma_q32(acc[0][0], a0, b0); PRIO0();
        STAGE_B(1, 1, t + 1);
        VM8(); BARRIER();
        // ph2: Q10(a1,b0) | reads b1 | stage A0.h0
        read_b32(b1, bR + 8192, hh, r7);
        PRIO1(); mfma_q32(acc[1][0], a1, b0); PRIO0();
        STAGE_A(0, 0, t + 2);
        BARRIER();
        // ph3: Q01(a0,b1) | stage B0.h0 | VM8
        PRIO1(); mfma_q32(acc[0][1], a0, b1); PRIO0();
        STAGE_B(0, 0, t + 2);
        VM8(); BARRIER();
        // ph4: Q11(a1,b1) | reads a0,b0 <- buf1.h0 | stage A0.h1 | VM8
        read_a32(a0, aR + 16384, hh, r7); read_b32(b0, bR + 16384, hh, r7);
        PRIO1(); mfma_q32(acc[1][1], a1, b1); PRIO0();
        STAGE_A(0, 1, t + 2);
        VM8(); BARRIER();
        // ph5: Q00 buf1 | reads a1 | stage B0.h1 | VM8
        read_a32(a1, aR + 16384 + 8192, hh, r7);
        PRIO1(); mfma_q32(acc[0][0], a0, b0); PRIO0();
        STAGE_B(0, 1, t + 2);
        VM8(); BARRIER();
        // ph6: Q10 | reads b1 | stage A1.h0
        read_b32(b1, bR + 16384 + 8192, hh, r7);
        PRIO1(); mfma_q32(acc[1][0], a1, b0); PRIO0();
        STAGE_A(1, 0, t + 3);
        BARRIER();
        // ph7: Q01 | stage B1.h0 | VM8
        PRIO1(); mfma_q32(acc[0][1], a0, b1); PRIO0();
        STAGE_B(1, 0, t + 3);
        VM8(); BARRIER();
        // ph8: Q11 | reads a0,b0 <- buf0.h0(t+2) | stage A1.h1 | VM8
        read_a32(a0, aR, hh, r7); read_b32(b0, bR, hh, r7);
        PRIO1(); mfma_q32(acc[1][1], a1, b1); PRIO0();
        STAGE_A(1, 1, t + 3);
        VM8(); BARRIER();
    }

    // Drain: buf0 = t=62, buf1 = t=63.
    read_a32(a1, aR + 8192, hh, r7);
    mfma_q32(acc[0][0], a0, b0);
    STAGE_B(1, 1, 63);
    VM8();
    BARRIER();
    read_b32(b1, bR + 8192, hh, r7);
    mfma_q32(acc[1][0], a1, b0);
    VM4();
    BARRIER();
    mfma_q32(acc[0][1], a0, b1);
    VM2();
    BARRIER();
    read_a32(a0, aR + 16384, hh, r7); read_b32(b0, bR + 16384, hh, r7);
    mfma_q32(acc[1][1], a1, b1);
    VM0();
    BARRIER();
    read_a32(a1, aR + 16384 + 8192, hh, r7);
    mfma_q32(acc[0][0], a0, b0);
    read_b32(b1, bR + 16384 + 8192, hh, r7);
    mfma_q32(acc[1][0], a1, b0);
    mfma_q32(acc[0][1], a0, b1);
    mfma_q32(acc[1][1], a1, b1);

#undef STAGE_A
#undef STAGE_B

    // Epilogue: 32x32 C/D layout: col = lane&31, row = (reg&3)+8*(reg>>2)+4*hh.
    // Lanes 0-31 cover 128 contiguous bytes per store; lanes 32-63 same cols
    // 4 rows down — two 128-B segments per instruction.
    float bvq[2];
#pragma unroll
    for (int qn = 0; qn < 2; ++qn)
        bvq[qn] = bias[n0 + wn * 64 + qn * 32 + l31];

#pragma unroll
    for (int qm = 0; qm < 2; ++qm)
#pragma unroll
        for (int qn = 0; qn < 2; ++qn)
#pragma unroll
            for (int mi = 0; mi < 2; ++mi) {
                const int rbase = m0 + wm * 128 + qm * 64 + mi * 32 + 4 * hh;
                const long cb = (long)n0 + wn * 64 + qn * 32 + l31;
#pragma unroll
                for (int r = 0; r < 16; ++r) {
                    int row = rbase + (r & 3) + 8 * (r >> 2);
                    C[(size_t)row * N_DIM + cb] = acc[qm][qn][mi][r] + bvq[qn];
                }
            }
}

// ---------------------------------------------------------------------------
extern "C" void kernel_launch(void* const* d_in, const int* in_sizes, int n_in,
                              void* d_out, int out_size, void* d_ws, size_t ws_size,
                              hipStream_t stream) {
    const float* x        = (const float*)d_in[0];  // [4096][4096]
    const int* packed     = (const int*)d_in[1];    // [11008][2048]
    const float* norms    = (const float*)d_in[2];  // [11008][32]
    const float* centroids= (const float*)d_in[3];  // [16]
    const float* signs1   = (const float*)d_in[4];  // [128]
    const float* signs2   = (const float*)d_in[5];  // [128]
    const float* bias     = (const float*)d_in[6];  // [11008]
    float* out            = (float*)d_out;          // [4096][11008]

    // Workspace: Mt (32 KB) | w_bf16 (90.2 MB) | z_bf16 (33.6 MB)
    unsigned short* Mt     = (unsigned short*)d_ws;
    unsigned short* w_bf16 = (unsigned short*)((char*)d_ws + 32768);
    unsigned short* z_bf16 = (unsigned short*)((char*)d_ws + 32768 + (size_t)N_DIM * K_DIM * 2);

    make_M_kernel<<<128, 128, 0, stream>>>(signs1, signs2, Mt);

    transform_x_kernel<<<(M_DIM / 256) * N_GROUPS, 512, 0, stream>>>(x, Mt, z_bf16);

    dequant_lut_kernel<<<N_DIM, 256, 0, stream>>>(
        packed, norms, centroids, (unsigned int*)w_bf16);

    gemm_bt_kernel<<<dim3((M_DIM / BM) * (N_DIM / BN)), 512, 0, stream>>>(
        z_bf16, w_bf16, bias, out);
}

// Round 5
// 589.034 us; speedup vs baseline: 1.0668x; 1.0668x over previous
//
#include <hip/hip_runtime.h>
#include <stdint.h>

// Problem constants
#define M_DIM 4096
#define K_DIM 4096
#define N_DIM 11008
#define N_GROUPS 32   // K_DIM / 128

typedef __attribute__((ext_vector_type(8))) short short8;   // 8 bf16 bit-patterns (4 VGPRs)
typedef __attribute__((ext_vector_type(4))) float floatx4;  // MFMA accumulator

__device__ __forceinline__ unsigned short f32_to_bf16(float f) {
    unsigned int u = __float_as_uint(f);
    unsigned int rounding = 0x7FFFu + ((u >> 16) & 1u);  // RNE
    return (unsigned short)((u + rounding) >> 16);
}

// ---------------------------------------------------------------------------
// Mt[i][j] = M[j][i] where M = H*diag(s2)*H*diag(s1) applied to x:
// z_i = sum_j M^T[i,j] x_j ; Mt[i][j] = s1[j]/128 * sum_a (-1)^(popc(i&a)+popc(a&j)) s2[a]
__global__ __launch_bounds__(128) void make_M_kernel(
    const float* __restrict__ signs1, const float* __restrict__ signs2,
    unsigned short* __restrict__ Mt)   // [128][128] bf16
{
    const int i = blockIdx.x;    // z-column
    const int j = threadIdx.x;   // x-row
    __shared__ float s2s[128];
    s2s[j] = signs2[j];
    __syncthreads();
    float acc = 0.f;
#pragma unroll 8
    for (int a = 0; a < 128; ++a) {
        int par = (__popc(i & a) + __popc(a & j)) & 1;
        acc += par ? -s2s[a] : s2s[a];
    }
    Mt[i * 128 + j] = f32_to_bf16(signs1[j] * acc * (1.0f / 128.0f));
}

// ---------------------------------------------------------------------------
// Z = X * M per 128-group (block-diagonal). One block = 256 rows x 1 group
// (4 sub-tiles of 64 rows), 512 threads. Mt staged once per block with
// B-fragments hoisted to registers; z stores LDS-staged -> uint4 coalesced.
__global__ __launch_bounds__(512) void transform_x_kernel(
    const float* __restrict__ x,            // [M_DIM][K_DIM] fp32
    const unsigned short* __restrict__ Mt,  // [128][128] bf16
    unsigned short* __restrict__ z)         // [M_DIM][K_DIM] bf16
{
    __shared__ __align__(16) short Ms[128 * 136];
    __shared__ __align__(16) short Xs[64 * 136];
    __shared__ __align__(16) short Ls[64 * 136];

    const int tid = threadIdx.x;
    const int wave = tid >> 6, lane = tid & 63;
    const int col16 = lane & 15, quad = lane >> 4;
    const int wr = wave >> 2;          // 0..1: 32-row slice
    const int wc = wave & 3;           // 0..3: 32-col slice
    const int g = blockIdx.x & 31;
    const int mblk = blockIdx.x >> 5;  // 0..15
    const int c0 = g * 128;
    const int mBase = mblk * 256;

    // stage Mt once (128 x 128 bf16 = 2048 uint4 chunks)
#pragma unroll
    for (int it = 0; it < 4; ++it) {
        int ch = tid + 512 * it;
        int row = ch >> 4, cc = ch & 15;
        *(uint4*)(Ms + row * 136 + cc * 8) = *(const uint4*)(Mt + (size_t)ch * 8);
    }
    __syncthreads();

    // hoist this wave's B-fragments (2 n-tiles x 4 ksteps) into registers
    short8 bf[2][4];
#pragma unroll
    for (int ni = 0; ni < 2; ++ni)
#pragma unroll
        for (int ks = 0; ks < 4; ++ks)
            bf[ni][ks] = *(const short8*)(Ms + (wc * 32 + ni * 16 + col16) * 136 + ks * 32 + quad * 8);

    for (int s = 0; s < 4; ++s) {
        __syncthreads();   // prior sub-tile's Xs reads + Ls stores complete
        // stage X sub-tile (64 x 128 fp32 -> bf16): 2048 float4, 4/thread
#pragma unroll
        for (int it = 0; it < 4; ++it) {
            int idx = tid + 512 * it;
            int row = idx >> 5, c4 = idx & 31;
            float4 v = *(const float4*)(x + (size_t)(mBase + s * 64 + row) * K_DIM + c0 + c4 * 4);
            uint2 o;
            o.x = (unsigned)f32_to_bf16(v.x) | ((unsigned)f32_to_bf16(v.y) << 16);
            o.y = (unsigned)f32_to_bf16(v.z) | ((unsigned)f32_to_bf16(v.w) << 16);
            *(uint2*)(Xs + row * 136 + c4 * 4) = o;
        }
        __syncthreads();

        // wave computes 32 rows x 32 cols: 2x2 tiles x 4 ksteps
        short8 af[2][4];
#pragma unroll
        for (int mi = 0; mi < 2; ++mi)
#pragma unroll
            for (int ks = 0; ks < 4; ++ks)
                af[mi][ks] = *(const short8*)(Xs + (wr * 32 + mi * 16 + col16) * 136 + ks * 32 + quad * 8);
        floatx4 acc2[2][2] = {};
#pragma unroll
        for (int ks = 0; ks < 4; ++ks)
#pragma unroll
            for (int mi = 0; mi < 2; ++mi)
#pragma unroll
                for (int ni = 0; ni < 2; ++ni)
                    acc2[mi][ni] = __builtin_amdgcn_mfma_f32_16x16x32_bf16(
                        af[mi][ks], bf[ni][ks], acc2[mi][ni], 0, 0, 0);

        // acc -> Ls (bf16), C/D layout: col=lane&15, row=quad*4+r
#pragma unroll
        for (int mi = 0; mi < 2; ++mi)
#pragma unroll
            for (int ni = 0; ni < 2; ++ni)
#pragma unroll
                for (int r = 0; r < 4; ++r)
                    Ls[(wr * 32 + mi * 16 + quad * 4 + r) * 136 + wc * 32 + ni * 16 + col16] =
                        f32_to_bf16(acc2[mi][ni][r]);
        __syncthreads();

        // coalesced store: 64 rows x 16 uint4-chunks, 2/thread
#pragma unroll
        for (int it = 0; it < 2; ++it) {
            int idx = tid + 512 * it;
            int row = idx >> 4, cc = idx & 15;
            uint4 v = *(const uint4*)(Ls + row * 136 + cc * 8);
            *(uint4*)(z + (size_t)(mBase + s * 64 + row) * K_DIM + c0 + cc * 8) = v;
        }
    }
}

// ---------------------------------------------------------------------------
// Dequant: w'[n, g*128+j] = norms[n,g] * centroids[idx]. R5: bank-replicated
// 16-entry nibble LUT -- lut[nib*32 + lane%32] so every lane always reads
// bank lane%32 (lanes l, l+32 share a bank = free 2-way). Structurally zero
// conflicts vs the old 256-entry byte-LUT's random-bank b64 reads.
__global__ __launch_bounds__(256) void dequant_lut_kernel(
    const int* __restrict__ packed,      // [N_DIM][2048] (one byte per int)
    const float* __restrict__ norms,     // [N_DIM][N_GROUPS]
    const float* __restrict__ centroids, // [16]
    unsigned int* __restrict__ w_out)    // [N_DIM][2048] two bf16 per uint
{
    __shared__ float lut[16 * 32];       // 2 KB: lut[nib*32 + rep]
    const int tid = threadIdx.x;
    lut[tid]       = centroids[tid >> 5];          // nibs 0..7
    lut[tid + 256] = centroids[(tid + 256) >> 5];  // nibs 8..15
    __syncthreads();

    const float* lutr = lut + (tid & 31);   // per-lane fixed bank

    const int row = blockIdx.x;
    const int g = tid >> 3;                 // 8 threads per 64-int group
    const float nrm = norms[row * N_GROUPS + g];
    const int* prow = packed + (size_t)row * 2048 + tid * 8;
    int4 pa = *(const int4*)(prow);
    int4 pb = *(const int4*)(prow + 4);
    int v[8] = {pa.x, pa.y, pa.z, pa.w, pb.x, pb.y, pb.z, pb.w};
    unsigned o[8];
#pragma unroll
    for (int q = 0; q < 8; ++q) {
        float clo = lutr[(v[q] & 15) << 5];
        float chi = lutr[((v[q] >> 4) & 15) << 5];
        o[q] = (unsigned)f32_to_bf16(clo * nrm) | ((unsigned)f32_to_bf16(chi * nrm) << 16);
    }
    unsigned* orow = w_out + (size_t)row * 2048 + tid * 8;
    *(uint4*)(orow)     = make_uint4(o[0], o[1], o[2], o[3]);
    *(uint4*)(orow + 4) = make_uint4(o[4], o[5], o[6], o[7]);
}

// ---------------------------------------------------------------------------
// GEMM: C[M][N] = Z[M][K] * W[N][K]^T + bias.
// R3 core restored verbatim (16x16x32 MFMA, proven 318 us / 0 conflicts);
// only change: nontemporal C stores (C stream is the L3-thrash suspect).
#define BM 256
#define BN 256
#define BK 64

typedef const __attribute__((address_space(1))) void* gvp_t;
typedef __attribute__((address_space(3))) void* svp_t;

#define BARRIER() do { asm volatile("" ::: "memory"); __builtin_amdgcn_s_barrier(); \
                       asm volatile("" ::: "memory"); } while (0)
#define VM8()   asm volatile("s_waitcnt vmcnt(8)" ::: "memory")
#define VM4()   asm volatile("s_waitcnt vmcnt(4)" ::: "memory")
#define VM2()   asm volatile("s_waitcnt vmcnt(2)" ::: "memory")
#define VM0()   asm volatile("s_waitcnt vmcnt(0)" ::: "memory")
#define PRIO1() __builtin_amdgcn_s_setprio(1)
#define PRIO0() __builtin_amdgcn_s_setprio(0)

// Read one quadrant's A frags: 4 M-frags x 2 k-slices. rb points at the
// (row0 = qhalf + wm*64 + col16) row; s0 = (quad ^ (col16&7))*8 shorts,
// the second k-slice slot is s0^32 ((4+quad)^sw == (quad^sw)^4).
__device__ __forceinline__ void read_a4(short8 (&dst)[4][2], const short* rb, int s0) {
#pragma unroll
    for (int fm = 0; fm < 4; ++fm) {
        dst[fm][0] = *(const short8*)(rb + fm * 1024 + s0);
        dst[fm][1] = *(const short8*)(rb + fm * 1024 + (s0 ^ 32));
    }
}
__device__ __forceinline__ void read_b2(short8 (&dst)[2][2], const short* rb, int s0) {
#pragma unroll
    for (int fn = 0; fn < 2; ++fn) {
        dst[fn][0] = *(const short8*)(rb + fn * 1024 + s0);
        dst[fn][1] = *(const short8*)(rb + fn * 1024 + (s0 ^ 32));
    }
}
// 16 MFMAs: one C-quadrant over K=64.
__device__ __forceinline__ void mfma_q(floatx4 (&acc)[4][2],
                                       const short8 (&a)[4][2], const short8 (&b)[2][2]) {
#pragma unroll
    for (int ks = 0; ks < 2; ++ks)
#pragma unroll
        for (int fm = 0; fm < 4; ++fm)
#pragma unroll
            for (int fn = 0; fn < 2; ++fn)
                acc[fm][fn] = __builtin_amdgcn_mfma_f32_16x16x32_bf16(
                    a[fm][ks], b[fn][ks], acc[fm][fn], 0, 0, 0);
}

__global__ __launch_bounds__(512, 2) void gemm_bt_kernel(
    const unsigned short* __restrict__ A,   // [M_DIM][K_DIM] bf16 bits (= Z)
    const unsigned short* __restrict__ B,   // [N_DIM][K_DIM] bf16 bits (= W')
    const float* __restrict__ bias,         // [N_DIM]
    float* __restrict__ C)                  // [M_DIM][N_DIM]
{
    // LDS: A[2 buf][256][64] | B[2 buf][256][64] bf16 = 128 KiB.
    __shared__ __align__(16) short smem[65536];
    short* As = smem;              // + buf*16384 (shorts)
    short* Bs = smem + 32768;

    const int tid = threadIdx.x;
    const int w = tid >> 6, lane = tid & 63;
    const int wm = w >> 2, wn = w & 3;          // 2 x 4 wave grid
    const int col16 = lane & 15, quad = lane >> 4;

    // nt-major grid order: XCD round-robin pins each XCD to 2 A-panels.
    const int bid = blockIdx.x;
    const int mt = bid & 15;                    // 0..15 (M/BM = 16 exactly)
    const int nt = bid >> 4;                    // 0..42
    const int m0 = mt * BM, n0 = nt * BN;

    // Staging: linear LDS dest; source column chunk XOR-swizzled so
    // ds_read slot ^ (row&7) recovers it (measured 0 bank conflicts).
    const int gc = (lane & 7) ^ (lane >> 3);
    const unsigned short* aSrc = A + (size_t)(m0 + w * 8 + (lane >> 3)) * K_DIM + gc * 8;
    const unsigned short* bSrc = B + (size_t)(n0 + (w >> 2) * 64 + (w & 3) * 8 + (lane >> 3)) * K_DIM + gc * 8;
    const int wOff = w * 512;

#define STAGE_A(BUF, H, KT) do { \
    __builtin_amdgcn_global_load_lds((gvp_t)(aSrc + (size_t)((H) * 64) * K_DIM + (KT) * 64), \
        (svp_t)(As + (BUF) * 16384 + (H) * 8192 + wOff), 16, 0, 0); \
    __builtin_amdgcn_global_load_lds((gvp_t)(aSrc + (size_t)((H) * 64 + 128) * K_DIM + (KT) * 64), \
        (svp_t)(As + (BUF) * 16384 + (H) * 8192 + 4096 + wOff), 16, 0, 0); \
} while (0)
#define STAGE_B(BUF, H, KT) do { \
    __builtin_amdgcn_global_load_lds((gvp_t)(bSrc + (size_t)((H) * 32) * K_DIM + (KT) * 64), \
        (svp_t)(Bs + (BUF) * 16384 + (H) * 8192 + wOff), 16, 0, 0); \
    __builtin_amdgcn_global_load_lds((gvp_t)(bSrc + (size_t)((H) * 32 + 128) * K_DIM + (KT) * 64), \
        (svp_t)(Bs + (BUF) * 16384 + (H) * 8192 + 4096 + wOff), 16, 0, 0); \
} while (0)

    // Fragment-read bases (loop-invariant; buf/half add compile-time offsets).
    const short* aR = As + (wm * 64 + col16) * 64;
    const short* bR = Bs + (wn * 32 + col16) * 64;
    const int s0 = (quad ^ (col16 & 7)) << 3;

    short8 a0[4][2], a1[4][2], b0[2][2], b1[2][2];
    floatx4 acc[2][2][4][2];   // [qm][qn][fm][fn]
#pragma unroll
    for (int i0 = 0; i0 < 2; ++i0)
#pragma unroll
        for (int i1 = 0; i1 < 2; ++i1)
#pragma unroll
            for (int i2 = 0; i2 < 4; ++i2)
#pragma unroll
                for (int i3 = 0; i3 < 2; ++i3)
                    acc[i0][i1][i2][i3] = (floatx4)0.0f;

    // SYNC LEDGER: identical to R3 (see R3 notes) — one barrier per phase,
    // vmcnt(8) keeps 4 half-tiles in flight, stage->read gap 4-5 phases.

    // Prologue = stages of virtual phases 2..7, then ph8 role.
    STAGE_A(0, 0, 0); STAGE_B(0, 0, 0);
    STAGE_A(0, 1, 0); STAGE_B(0, 1, 0);
    STAGE_A(1, 0, 1); STAGE_B(1, 0, 1);
    VM8();
    BARRIER();
    read_a4(a0, aR, s0); read_b2(b0, bR, s0);
    STAGE_A(1, 1, 1);
    VM8();
    BARRIER();

    const int NIT = K_DIM / (2 * BK) - 1;   // 31 full iterations + drain
    for (int i = 0; i < NIT; ++i) {
        const int t = 2 * i;
        // ph1: Q00(a0,b0) | reads a1 | stage B1.h1 | VM8
        read_a4(a1, aR + 8192, s0);
        PRIO1(); mfma_q(acc[0][0], a0, b0); PRIO0();
        STAGE_B(1, 1, t + 1);
        VM8(); BARRIER();
        // ph2: Q10(a1,b0) | reads b1 | stage A0.h0
        read_b2(b1, bR + 8192, s0);
        PRIO1(); mfma_q(acc[1][0], a1, b0); PRIO0();
        STAGE_A(0, 0, t + 2);
        BARRIER();
        // ph3: Q01(a0,b1) | stage B0.h0 | VM8
        PRIO1(); mfma_q(acc[0][1], a0, b1); PRIO0();
        STAGE_B(0, 0, t + 2);
        VM8(); BARRIER();
        // ph4: Q11(a1,b1) | reads a0,b0 <- buf1.h0 | stage A0.h1 | VM8
        read_a4(a0, aR + 16384, s0); read_b2(b0, bR + 16384, s0);
        PRIO1(); mfma_q(acc[1][1], a1, b1); PRIO0();
        STAGE_A(0, 1, t + 2);
        VM8(); BARRIER();
        // ph5: Q00(a0,b0) buf1 | reads a1 | stage B0.h1 | VM8
        read_a4(a1, aR + 16384 + 8192, s0);
        PRIO1(); mfma_q(acc[0][0], a0, b0); PRIO0();
        STAGE_B(0, 1, t + 2);
        VM8(); BARRIER();
        // ph6: Q10(a1,b0) | reads b1 | stage A1.h0
        read_b2(b1, bR + 16384 + 8192, s0);
        PRIO1(); mfma_q(acc[1][0], a1, b0); PRIO0();
        STAGE_A(1, 0, t + 3);
        BARRIER();
        // ph7: Q01(a0,b1) | stage B1.h0 | VM8
        PRIO1(); mfma_q(acc[0][1], a0, b1); PRIO0();
        STAGE_B(1, 0, t + 3);
        VM8(); BARRIER();
        // ph8: Q11(a1,b1) | reads a0,b0 <- buf0.h0(t+2) | stage A1.h1 | VM8
        read_a4(a0, aR, s0); read_b2(b0, bR, s0);
        PRIO1(); mfma_q(acc[1][1], a1, b1); PRIO0();
        STAGE_A(1, 1, t + 3);
        VM8(); BARRIER();
    }

    // Drain: buf0 = t=62, buf1 = t=63 (B1.h1 of 63 staged at dph1).
    read_a4(a1, aR + 8192, s0);
    mfma_q(acc[0][0], a0, b0);
    STAGE_B(1, 1, 63);
    VM8();
    BARRIER();
    read_b2(b1, bR + 8192, s0);
    mfma_q(acc[1][0], a1, b0);
    VM4();
    BARRIER();
    mfma_q(acc[0][1], a0, b1);
    VM2();
    BARRIER();
    read_a4(a0, aR + 16384, s0); read_b2(b0, bR + 16384, s0);
    mfma_q(acc[1][1], a1, b1);
    VM0();
    BARRIER();
    read_a4(a1, aR + 16384 + 8192, s0);
    mfma_q(acc[0][0], a0, b0);
    read_b2(b1, bR + 16384 + 8192, s0);
    mfma_q(acc[1][0], a1, b0);
    mfma_q(acc[0][1], a0, b1);
    mfma_q(acc[1][1], a1, b1);

#undef STAGE_A
#undef STAGE_B

    // Epilogue: bias + nontemporal stores (C is write-once streaming; keep it
    // out of L3 so B panels stay resident).
    float bv[2][2];
#pragma unroll
    for (int qn = 0; qn < 2; ++qn)
#pragma unroll
        for (int fn = 0; fn < 2; ++fn)
            bv[qn][fn] = bias[n0 + wn * 64 + qn * 32 + fn * 16 + col16];

#pragma unroll
    for (int qm = 0; qm < 2; ++qm)
#pragma unroll
        for (int fm = 0; fm < 4; ++fm)
#pragma unroll
            for (int r = 0; r < 4; ++r) {
                float* crow = C + (size_t)(m0 + wm * 128 + qm * 64 + fm * 16 + quad * 4 + r) * N_DIM
                              + n0 + wn * 64 + col16;
#pragma unroll
                for (int qn = 0; qn < 2; ++qn)
#pragma unroll
                    for (int fn = 0; fn < 2; ++fn)
                        __builtin_nontemporal_store(acc[qm][qn][fm][fn][r] + bv[qn][fn],
                                                    &crow[qn * 32 + fn * 16]);
            }
}

// ---------------------------------------------------------------------------
extern "C" void kernel_launch(void* const* d_in, const int* in_sizes, int n_in,
                              void* d_out, int out_size, void* d_ws, size_t ws_size,
                              hipStream_t stream) {
    const float* x        = (const float*)d_in[0];  // [4096][4096]
    const int* packed     = (const int*)d_in[1];    // [11008][2048]
    const float* norms    = (const float*)d_in[2];  // [11008][32]
    const float* centroids= (const float*)d_in[3];  // [16]
    const float* signs1   = (const float*)d_in[4];  // [128]
    const float* signs2   = (const float*)d_in[5];  // [128]
    const float* bias     = (const float*)d_in[6];  // [11008]
    float* out            = (float*)d_out;          // [4096][11008]

    // Workspace: Mt (32 KB) | w_bf16 (90.2 MB) | z_bf16 (33.6 MB)
    unsigned short* Mt     = (unsigned short*)d_ws;
    unsigned short* w_bf16 = (unsigned short*)((char*)d_ws + 32768);
    unsigned short* z_bf16 = (unsigned short*)((char*)d_ws + 32768 + (size_t)N_DIM * K_DIM * 2);

    make_M_kernel<<<128, 128, 0, stream>>>(signs1, signs2, Mt);

    transform_x_kernel<<<(M_DIM / 256) * N_GROUPS, 512, 0, stream>>>(x, Mt, z_bf16);

    dequant_lut_kernel<<<N_DIM, 256, 0, stream>>>(
        packed, norms, centroids, (unsigned int*)w_bf16);

    gemm_bt_kernel<<<dim3((M_DIM / BM) * (N_DIM / BN)), 512, 0, stream>>>(
        z_bf16, w_bf16, bias, out);
}